// Round 4
// baseline (36.785 us; speedup 1.0000x reference)
//
#include <hip/hip_runtime.h>

#define VOLD 256
// Cell = 8(x) x 16(y) x 32(z) voxels; cell grid 32 x 16 x 8 = 4096 cells.
// z-extent 32 floats = 128 B -> each block owns full aligned cache lines.
#define CXD 8
#define CYD 16
#define CZD 32
#define NCELLS 4096
#define CAP 80          // max gaussians per cell (avg ~12.5)
#define WPG 56          // per-gaussian weights: 8(x) + 16(y) + 32(z)

// ---- Phase 0: pack per-gaussian cell-space bbox into one int ---------------
// bits: c0x[0:5) c1x[5:10) c0y[10:14) c1y[14:18) c0z[18:21) c1z[21:24)
__global__ __launch_bounds__(256) void prep_kernel(
    const float* __restrict__ centers, const float* __restrict__ sigmas,
    int* __restrict__ bbox, int N)
{
    const int g = blockIdx.x * 256 + threadIdx.x;
    if (g >= N) return;
    const float sig = sigmas[g];
    const float cut = 3.0f * sig * 255.0f;

    int mini[3], maxi[3];
    #pragma unroll
    for (int a = 0; a < 3; ++a) {
        const float cv   = centers[3 * g + a] * 255.0f;
        const float minf = fmaxf(cv - cut, 0.0f);
        const float maxf = fminf(cv + cut, 255.0f);
        mini[a] = (int)floorf(minf);
        maxi[a] = min((int)floorf(maxf) + 1, VOLD);   // exclusive
    }
    int pack = 0;
    pack |=  (mini[0] >> 3)        | (((maxi[0] - 1) >> 3) << 5);    // x: cells of 8
    pack |= ((mini[1] >> 4) << 10) | (((maxi[1] - 1) >> 4) << 14);   // y: cells of 16
    pack |= ((mini[2] >> 5) << 18) | (((maxi[2] - 1) >> 5) << 21);   // z: cells of 32
    bbox[g] = pack;
}

// ---- Phase 1: per-cell self-binning gather + separable accumulate ----------
__global__ __launch_bounds__(256) void splat_kernel(
    const float* __restrict__ centers, const float* __restrict__ sigmas,
    const float* __restrict__ intens, const int* __restrict__ bbox,
    float* __restrict__ vol, int N)
{
    const int cell = blockIdx.x;
    const int czc = cell & 7;            // 0..7
    const int cyc = (cell >> 3) & 15;    // 0..15
    const int cxc = cell >> 7;           // 0..31
    const int vx0 = cxc * CXD, vy0 = cyc * CYD, vz0 = czc * CZD;
    const int t = threadIdx.x;

    __shared__ int   lcnt;
    __shared__ int   list[CAP];
    __shared__ float wx[CAP][CXD];       // intensity folded in
    __shared__ float wy[CAP][CYD];
    __shared__ float wz[CAP][CZD];       // ~18 KB total

    if (t == 0) lcnt = 0;
    __syncthreads();

    // Scan all packed bboxes; LDS-compact the hits for this cell.
    for (int g = t; g < N; g += 256) {
        const int pk = bbox[g];
        const int x0 =  pk        & 31, x1 = (pk >> 5)  & 31;
        const int y0 = (pk >> 10) & 15, y1 = (pk >> 14) & 15;
        const int z0 = (pk >> 18) & 7,  z1 = (pk >> 21) & 7;
        if (cxc >= x0 && cxc <= x1 && cyc >= y0 && cyc <= y1 &&
            czc >= z0 && czc <= z1) {
            const int p = atomicAdd(&lcnt, 1);
            if (p < CAP) list[p] = g;
        }
    }
    __syncthreads();
    const int K = min(lcnt, CAP);

    // Weight phase: K * 56 separable exp weights.
    for (int i = t; i < K * WPG; i += 256) {
        const int g = i / WPG;
        const int r = i - g * WPG;
        const int gi = list[g];

        int axis, o, base;
        if (r < CXD)            { axis = 0; o = r;              base = vx0; }
        else if (r < CXD + CYD) { axis = 1; o = r - CXD;        base = vy0; }
        else                    { axis = 2; o = r - CXD - CYD;  base = vz0; }

        const float cn  = centers[3 * gi + axis];
        const float sig = sigmas[gi];
        const float cv  = cn * 255.0f;
        const float cut = 3.0f * sig * 255.0f;
        const int mini = (int)floorf(fmaxf(cv - cut, 0.0f));
        const int maxi = min((int)floorf(fminf(cv + cut, 255.0f)) + 1, VOLD);

        const int idx = base + o;
        float wv = 0.0f;
        if (idx >= mini && idx < maxi) {
            const float d = (float)idx * (1.0f / 255.0f) - cn;
            const float inv2s2 = 0.5f / (sig * sig);
            wv = __expf(-d * d * inv2s2);
            if (axis == 0) wv *= intens[gi];
        }
        if (axis == 0)      wx[g][o] = wv;
        else if (axis == 1) wy[g][o] = wv;
        else                wz[g][o] = wv;
    }
    __syncthreads();

    // Thread tile: 4 x-values (xh half) x 1 y x 4 z (z-quad).
    const int zq = t & 7;          // z-quad -> z = 4*zq
    const int ty = (t >> 3) & 15;  // y
    const int xh = t >> 7;         // x half -> x = 4*xh + i

    float acc[4][4];               // [x][z]
    #pragma unroll
    for (int i = 0; i < 4; ++i)
        #pragma unroll
        for (int j = 0; j < 4; ++j) acc[i][j] = 0.0f;

    for (int k = 0; k < K; ++k) {
        const float wyv = wy[k][ty];
        if (wyv == 0.0f) continue;
        const float4 wz4 = *(const float4*)&wz[k][4 * zq];
        const float4 wx4 = *(const float4*)&wx[k][4 * xh];
        float tmp[4];
        tmp[0] = wyv * wz4.x; tmp[1] = wyv * wz4.y;
        tmp[2] = wyv * wz4.z; tmp[3] = wyv * wz4.w;
        const float xs[4] = {wx4.x, wx4.y, wx4.z, wx4.w};
        #pragma unroll
        for (int i = 0; i < 4; ++i)
            #pragma unroll
            for (int j = 0; j < 4; ++j)
                acc[i][j] += xs[i] * tmp[j];
    }

    // Coalesced full-line stores: 4 x dwordx4 per thread.
    #pragma unroll
    for (int i = 0; i < 4; ++i) {
        const int x = 4 * xh + i;
        const size_t lin = (size_t)(vx0 + x) * (VOLD * VOLD)
                         + (size_t)(vy0 + ty) * VOLD + (size_t)(vz0 + 4 * zq);
        *(float4*)&vol[lin] = *(const float4*)&acc[i][0];
    }
}

extern "C" void kernel_launch(void* const* d_in, const int* in_sizes, int n_in,
                              void* d_out, int out_size, void* d_ws, size_t ws_size,
                              hipStream_t stream) {
    const float* centers = (const float*)d_in[0];   // (N,3)
    const float* sigmas  = (const float*)d_in[1];   // (N,)
    const float* intens  = (const float*)d_in[2];   // (N,)
    float* vol = (float*)d_out;
    const int N = in_sizes[1];                      // 4000

    int* bbox = (int*)d_ws;                         // N packed bboxes (16 KB)

    prep_kernel<<<(N + 255) / 256, 256, 0, stream>>>(centers, sigmas, bbox, N);
    splat_kernel<<<NCELLS, 256, 0, stream>>>(centers, sigmas, intens, bbox, vol, N);
}

// Round 6
// 31.126 us; speedup vs baseline: 1.1818x; 1.1818x over previous
//
#include <hip/hip_runtime.h>

#define VOLD 256
// Cell = 8(x) x 16(y) x 32(z); grid 32 x 16 x 8 = 4096 cells.
#define CXD 8
#define CYD 16
#define CZD 32
#define NCELLS 4096
#define NPAD 4096        // bbox array padded to 4096 (sentinels) for int4 scan
#define CAP 80

typedef float nfloat4 __attribute__((ext_vector_type(4)));   // native vec for NT store

// ---- Phase 0: packed cell-space bbox per gaussian (+ sentinels) ------------
// bits: c0x[0:5) c1x[5:10) c0y[10:14) c1y[14:18) c0z[18:21) c1z[21:24)
__global__ __launch_bounds__(256) void prep_kernel(
    const float* __restrict__ centers, const float* __restrict__ sigmas,
    int* __restrict__ bbox, int N)
{
    const int g = blockIdx.x * 256 + threadIdx.x;
    if (g >= NPAD) return;
    if (g >= N) { bbox[g] = 31; return; }   // x0=31,x1=0 -> never matches

    const float sig = sigmas[g];
    const float cut = 3.0f * sig * 255.0f;
    int mini[3], maxi[3];
    #pragma unroll
    for (int a = 0; a < 3; ++a) {
        const float cv   = centers[3 * g + a] * 255.0f;
        mini[a] = (int)floorf(fmaxf(cv - cut, 0.0f));
        maxi[a] = min((int)floorf(fminf(cv + cut, 255.0f)) + 1, VOLD);  // excl
    }
    int pack = 0;
    pack |=  (mini[0] >> 3)        | (((maxi[0] - 1) >> 3) << 5);    // x /8
    pack |= ((mini[1] >> 4) << 10) | (((maxi[1] - 1) >> 4) << 14);   // y /16
    pack |= ((mini[2] >> 5) << 18) | (((maxi[2] - 1) >> 5) << 21);   // z /32
    bbox[g] = pack;
}

// ---- Phase 1: self-binning gather + pipelined separable accumulate ---------
__global__ __launch_bounds__(256) void splat_kernel(
    const float* __restrict__ centers, const float* __restrict__ sigmas,
    const float* __restrict__ intens, const int* __restrict__ bbox,
    float* __restrict__ vol)
{
    const int cell = blockIdx.x;
    const int czc = cell & 7;
    const int cyc = (cell >> 3) & 15;
    const int cxc = cell >> 7;
    const int vx0 = cxc * CXD, vy0 = cyc * CYD, vz0 = czc * CZD;
    const int t = threadIdx.x;

    __shared__ int   lcnt;
    __shared__ int   list[CAP];
    __shared__ float wx[CAP][CXD];
    __shared__ float wy[CAP][CYD];
    __shared__ float wz[CAP][CZD];   // ~18 KB total

    if (t == 0) lcnt = 0;
    __syncthreads();

    // Scan: 4 iterations of int4 (4096 packed bboxes incl. sentinels).
    #pragma unroll
    for (int j = 0; j < 4; ++j) {
        const int idx4 = t + 256 * j;
        const int4 p4 = ((const int4*)bbox)[idx4];
        const int pks[4] = {p4.x, p4.y, p4.z, p4.w};
        #pragma unroll
        for (int u = 0; u < 4; ++u) {
            const int pk = pks[u];
            const int x0 =  pk        & 31, x1 = (pk >> 5)  & 31;
            const int y0 = (pk >> 10) & 15, y1 = (pk >> 14) & 15;
            const int z0 = (pk >> 18) & 7,  z1 = (pk >> 21) & 7;
            if (cxc >= x0 && cxc <= x1 && cyc >= y0 && cyc <= y1 &&
                czc >= z0 && czc <= z1) {
                const int p = atomicAdd(&lcnt, 1);
                if (p < CAP) list[p] = 4 * idx4 + u;
            }
        }
    }
    __syncthreads();
    const int K = min(lcnt, CAP);

    // Weight phase: three per-axis loops (shift/mask indexing, no div).
    for (int i = t; i < K * CXD; i += 256) {
        const int g = i >> 3, o = i & 7, gi = list[g];
        const float cn = centers[3 * gi], sig = sigmas[gi];
        const float cv = cn * 255.0f, cut = 3.0f * sig * 255.0f;
        const int mini = (int)floorf(fmaxf(cv - cut, 0.0f));
        const int maxi = min((int)floorf(fminf(cv + cut, 255.0f)) + 1, VOLD);
        const int idx = vx0 + o;
        float wv = 0.0f;
        if (idx >= mini && idx < maxi) {
            const float d = (float)idx * (1.0f / 255.0f) - cn;
            wv = __expf(-d * d * (0.5f / (sig * sig))) * intens[gi];
        }
        wx[g][o] = wv;
    }
    for (int i = t; i < K * CYD; i += 256) {
        const int g = i >> 4, o = i & 15, gi = list[g];
        const float cn = centers[3 * gi + 1], sig = sigmas[gi];
        const float cv = cn * 255.0f, cut = 3.0f * sig * 255.0f;
        const int mini = (int)floorf(fmaxf(cv - cut, 0.0f));
        const int maxi = min((int)floorf(fminf(cv + cut, 255.0f)) + 1, VOLD);
        const int idx = vy0 + o;
        float wv = 0.0f;
        if (idx >= mini && idx < maxi) {
            const float d = (float)idx * (1.0f / 255.0f) - cn;
            wv = __expf(-d * d * (0.5f / (sig * sig)));
        }
        wy[g][o] = wv;
    }
    for (int i = t; i < K * CZD; i += 256) {
        const int g = i >> 5, o = i & 31, gi = list[g];
        const float cn = centers[3 * gi + 2], sig = sigmas[gi];
        const float cv = cn * 255.0f, cut = 3.0f * sig * 255.0f;
        const int mini = (int)floorf(fmaxf(cv - cut, 0.0f));
        const int maxi = min((int)floorf(fminf(cv + cut, 255.0f)) + 1, VOLD);
        const int idx = vz0 + o;
        float wv = 0.0f;
        if (idx >= mini && idx < maxi) {
            const float d = (float)idx * (1.0f / 255.0f) - cn;
            wv = __expf(-d * d * (0.5f / (sig * sig)));
        }
        wz[g][o] = wv;
    }
    __syncthreads();

    // Accumulate: software-pipelined over k (loads of k+1 before FMAs of k).
    const int zq = t & 7;          // z = 4*zq..4*zq+3
    const int ty = (t >> 3) & 15;  // y
    const int xh = t >> 7;         // x = 4*xh..4*xh+3

    float acc[4][4];
    #pragma unroll
    for (int i = 0; i < 4; ++i)
        #pragma unroll
        for (int j = 0; j < 4; ++j) acc[i][j] = 0.0f;

    float  cw = wy[0][ty];
    float4 cz = *(const float4*)&wz[0][4 * zq];
    float4 cx = *(const float4*)&wx[0][4 * xh];

    for (int k = 0; k < K; ++k) {
        const int kn = (k + 1 < K) ? (k + 1) : k;   // clamped, branch-free
        const float  nw = wy[kn][ty];
        const float4 nz = *(const float4*)&wz[kn][4 * zq];
        const float4 nx = *(const float4*)&wx[kn][4 * xh];

        if (cw != 0.0f) {
            const float t0 = cw * cz.x, t1 = cw * cz.y;
            const float t2 = cw * cz.z, t3 = cw * cz.w;
            const float xs[4] = {cx.x, cx.y, cx.z, cx.w};
            #pragma unroll
            for (int i = 0; i < 4; ++i) {
                acc[i][0] += xs[i] * t0;
                acc[i][1] += xs[i] * t1;
                acc[i][2] += xs[i] * t2;
                acc[i][3] += xs[i] * t3;
            }
        }
        cw = nw; cz = nz; cx = nx;
    }

    // Full-line nontemporal stores: 4 x dwordx4 per thread.
    #pragma unroll
    for (int i = 0; i < 4; ++i) {
        const int x = 4 * xh + i;
        const size_t lin = (size_t)(vx0 + x) * (VOLD * VOLD)
                         + (size_t)(vy0 + ty) * VOLD + (size_t)(vz0 + 4 * zq);
        nfloat4 v;
        v.x = acc[i][0]; v.y = acc[i][1]; v.z = acc[i][2]; v.w = acc[i][3];
        __builtin_nontemporal_store(v, (nfloat4*)&vol[lin]);
    }
}

extern "C" void kernel_launch(void* const* d_in, const int* in_sizes, int n_in,
                              void* d_out, int out_size, void* d_ws, size_t ws_size,
                              hipStream_t stream) {
    const float* centers = (const float*)d_in[0];   // (N,3)
    const float* sigmas  = (const float*)d_in[1];   // (N,)
    const float* intens  = (const float*)d_in[2];   // (N,)
    float* vol = (float*)d_out;
    const int N = in_sizes[1];                      // 4000

    int* bbox = (int*)d_ws;                         // NPAD packed bboxes (16 KB)

    prep_kernel<<<NPAD / 256, 256, 0, stream>>>(centers, sigmas, bbox, N);
    splat_kernel<<<NCELLS, 256, 0, stream>>>(centers, sigmas, intens, bbox, vol);
}

// Round 7
// 28.855 us; speedup vs baseline: 1.2748x; 1.0787x over previous
//
#include <hip/hip_runtime.h>

#define VOLD 256
// Cell = 8(x) x 16(y) x 32(z); grid 32 x 16 x 8 = 4096 cells, one kernel.
#define CXD 8
#define CYD 16
#define CZD 32
#define NCELLS 4096
#define CAP 80

typedef float nfloat4 __attribute__((ext_vector_type(4)));

__global__ __launch_bounds__(256) void splat_kernel(
    const float* __restrict__ centers, const float* __restrict__ sigmas,
    const float* __restrict__ intens, float* __restrict__ vol, int N)
{
    const int cell = blockIdx.x;
    const int czc = cell & 7;
    const int cyc = (cell >> 3) & 15;
    const int cxc = cell >> 7;
    const int vx0 = cxc * CXD, vy0 = cyc * CYD, vz0 = czc * CZD;
    const int t = threadIdx.x;

    __shared__ int    lcnt;
    __shared__ float4 pc4[CAP];          // cx, cy, cz, sigma
    __shared__ float  pint[CAP];         // intensity
    __shared__ float  wx[CAP][CXD];
    __shared__ float  wy[CAP][CYD];
    __shared__ float  wz[CAP][CZD];      // ~19.5 KB total -> 8 blocks/CU

    if (t == 0) lcnt = 0;
    __syncthreads();

    // ---- Scan: direct float-domain bbox-overlap test (no prep kernel). ----
    // Gaussian hits cell iff  max over 6 of {cv - AHI, ALO - cv}  <  cut,
    // with 0.5-voxel margin: only false POSITIVES (their weights are 0).
    const float axh = (float)(vx0 + CXD) + 0.5f, axl = (float)vx0 - 0.5f;
    const float ayh = (float)(vy0 + CYD) + 0.5f, ayl = (float)vy0 - 0.5f;
    const float azh = (float)(vz0 + CZD) + 0.5f, azl = (float)vz0 - 0.5f;

    for (int g = t; g < N; g += 256) {
        const float cx = centers[3 * g], cy = centers[3 * g + 1], cz = centers[3 * g + 2];
        const float sg = sigmas[g];
        const float cut = sg * 765.0f;                      // 3*sigma*255
        const float m1 = fmaxf(fmaxf(fmaf(cx, 255.0f, -axh),
                                     fmaf(cy, 255.0f, -ayh)),
                                     fmaf(cz, 255.0f, -azh));
        const float m2 = fmaxf(fmaxf(fmaf(-cx, 255.0f, axl),
                                     fmaf(-cy, 255.0f, ayl)),
                                     fmaf(-cz, 255.0f, azl));
        if (fmaxf(m1, m2) < cut) {
            const int p = atomicAdd(&lcnt, 1);
            if (p < CAP) {
                pc4[p]  = make_float4(cx, cy, cz, sg);
                pint[p] = intens[g];
            }
        }
    }
    __syncthreads();
    const int K = min(lcnt, CAP);

    // ---- Weights: per-axis loops, all params from LDS (no global loads). ----
    for (int i = t; i < K * CXD; i += 256) {
        const int g = i >> 3, o = i & 7;
        const float4 p = pc4[g];
        const float cn = p.x, sig = p.w;
        const float cv = cn * 255.0f, cut = 3.0f * sig * 255.0f;
        const int mini = (int)floorf(fmaxf(cv - cut, 0.0f));
        const int maxi = min((int)floorf(fminf(cv + cut, 255.0f)) + 1, VOLD);
        const int idx = vx0 + o;
        float wv = 0.0f;
        if (idx >= mini && idx < maxi) {
            const float d = (float)idx * (1.0f / 255.0f) - cn;
            wv = __expf(-d * d * (0.5f / (sig * sig))) * pint[g];
        }
        wx[g][o] = wv;
    }
    for (int i = t; i < K * CYD; i += 256) {
        const int g = i >> 4, o = i & 15;
        const float4 p = pc4[g];
        const float cn = p.y, sig = p.w;
        const float cv = cn * 255.0f, cut = 3.0f * sig * 255.0f;
        const int mini = (int)floorf(fmaxf(cv - cut, 0.0f));
        const int maxi = min((int)floorf(fminf(cv + cut, 255.0f)) + 1, VOLD);
        const int idx = vy0 + o;
        float wv = 0.0f;
        if (idx >= mini && idx < maxi) {
            const float d = (float)idx * (1.0f / 255.0f) - cn;
            wv = __expf(-d * d * (0.5f / (sig * sig)));
        }
        wy[g][o] = wv;
    }
    for (int i = t; i < K * CZD; i += 256) {
        const int g = i >> 5, o = i & 31;
        const float4 p = pc4[g];
        const float cn = p.z, sig = p.w;
        const float cv = cn * 255.0f, cut = 3.0f * sig * 255.0f;
        const int mini = (int)floorf(fmaxf(cv - cut, 0.0f));
        const int maxi = min((int)floorf(fminf(cv + cut, 255.0f)) + 1, VOLD);
        const int idx = vz0 + o;
        float wv = 0.0f;
        if (idx >= mini && idx < maxi) {
            const float d = (float)idx * (1.0f / 255.0f) - cn;
            wv = __expf(-d * d * (0.5f / (sig * sig)));
        }
        wz[g][o] = wv;
    }
    __syncthreads();

    // ---- Accumulate: wave-uniform y-block => REAL whole-wave zero-skip. ----
    const int zq = t & 7;            // z = 4*zq .. 4*zq+3
    const int x  = (t >> 3) & 7;     // x
    const int w  = t >> 6;           // wave id: y in [4w, 4w+4)

    float acc[4][4];                 // [yy][z-in-quad]
    #pragma unroll
    for (int i = 0; i < 4; ++i)
        #pragma unroll
        for (int j = 0; j < 4; ++j) acc[i][j] = 0.0f;

    float4 cy4 = *(const float4*)&wy[0][4 * w];   // broadcast (wave-uniform)
    float4 cz4 = *(const float4*)&wz[0][4 * zq];
    float  cxw = wx[0][x];

    for (int k = 0; k < K; ++k) {
        const int kn = (k + 1 < K) ? (k + 1) : k;     // clamped prefetch
        const float4 ny4 = *(const float4*)&wy[kn][4 * w];
        const float4 nz4 = *(const float4*)&wz[kn][4 * zq];
        const float  nxw = wx[kn][x];

        // cy4 identical across the wave -> this branch is wave-uniform;
        // cxw adds a per-lane mask (and full skip when all x invalid).
        if ((cxw != 0.0f) &
            ((cy4.x != 0.0f) | (cy4.y != 0.0f) | (cy4.z != 0.0f) | (cy4.w != 0.0f))) {
            const float p0 = cy4.x * cxw, p1 = cy4.y * cxw;
            const float p2 = cy4.z * cxw, p3 = cy4.w * cxw;
            acc[0][0] += p0 * cz4.x; acc[0][1] += p0 * cz4.y;
            acc[0][2] += p0 * cz4.z; acc[0][3] += p0 * cz4.w;
            acc[1][0] += p1 * cz4.x; acc[1][1] += p1 * cz4.y;
            acc[1][2] += p1 * cz4.z; acc[1][3] += p1 * cz4.w;
            acc[2][0] += p2 * cz4.x; acc[2][1] += p2 * cz4.y;
            acc[2][2] += p2 * cz4.z; acc[2][3] += p2 * cz4.w;
            acc[3][0] += p3 * cz4.x; acc[3][1] += p3 * cz4.y;
            acc[3][2] += p3 * cz4.z; acc[3][3] += p3 * cz4.w;
        }
        cy4 = ny4; cz4 = nz4; cxw = nxw;
    }

    // ---- Full-line nontemporal stores: 4 x dwordx4 per thread. ----
    #pragma unroll
    for (int yy = 0; yy < 4; ++yy) {
        const int y = 4 * w + yy;
        const size_t lin = (size_t)(vx0 + x) * (VOLD * VOLD)
                         + (size_t)(vy0 + y) * VOLD + (size_t)(vz0 + 4 * zq);
        nfloat4 v;
        v.x = acc[yy][0]; v.y = acc[yy][1]; v.z = acc[yy][2]; v.w = acc[yy][3];
        __builtin_nontemporal_store(v, (nfloat4*)&vol[lin]);
    }
}

extern "C" void kernel_launch(void* const* d_in, const int* in_sizes, int n_in,
                              void* d_out, int out_size, void* d_ws, size_t ws_size,
                              hipStream_t stream) {
    const float* centers = (const float*)d_in[0];   // (N,3)
    const float* sigmas  = (const float*)d_in[1];   // (N,)
    const float* intens  = (const float*)d_in[2];   // (N,)
    float* vol = (float*)d_out;
    const int N = in_sizes[1];                      // 4000

    splat_kernel<<<NCELLS, 256, 0, stream>>>(centers, sigmas, intens, vol, N);
}